// Round 13
// baseline (33.737 us; speedup 1.0000x reference)
//
#include <hip/hip_runtime.h>
#include <hip/hip_bf16.h>

typedef float f4 __attribute__((ext_vector_type(4)));
typedef float f32x4 __attribute__((ext_vector_type(4)));
typedef short s16x8 __attribute__((ext_vector_type(8)));

// Max-TLP MFMA kernel. Block = 512 thr = 8 waves, owns 16 tokens.
// Wave w handles k-eighth [w*128,+128): 4 MFMA steps of k=32.
// Lane l: token/expert n = l&15, k-group kg = l>>4 (8 contiguous floats).
// Per step: 4 dwordx4 loads (A pair + B pair), packed to bf16 via
// v_cvt_pk_bf16_f32, one mfma_f32_16x16x32_bf16. 1-step lookahead keeps
// 8 loads (8 KB) in flight per wave; the design target is VGPR <= 64 so
// 8 waves/SIMD can be resident (R4..R12 all had 2-4 fat waves/SIMD and
// clustered at 27.4-28.1 us = TLP-starved latency wall).
// Epilogue: 8 k-partials combined via 8 KB LDS, 16 parallel softmaxes.

#define TPB 16   // tokens per block

__device__ __forceinline__ s16x8 pack8(f4 a, f4 b) {
  union { s16x8 v; __hip_bfloat162 h[4]; } u;
  u.h[0] = __float22bfloat162_rn({a.x, a.y});
  u.h[1] = __float22bfloat162_rn({a.z, a.w});
  u.h[2] = __float22bfloat162_rn({b.x, b.y});
  u.h[3] = __float22bfloat162_rn({b.z, b.w});
  return u.v;
}

__global__ __launch_bounds__(512)
void moa_k8(const float* __restrict__ tok,
            const float* __restrict__ Wq,
            const float* __restrict__ Wk,
            const float* __restrict__ Wv,
            float* __restrict__ out) {
  __shared__ float clds[8 * 256];                 // 8 KB: [wave][16 tok][16 col]
  const int tid  = threadIdx.x;
  const int wv   = tid >> 6;                      // 0..7: k-eighth
  const int lane = tid & 63;
  const int n    = lane & 15;                     // token row / expert col
  const int kg   = lane >> 4;                     // k-group of 8
  const int kb   = wv * 128;                      // wave's k-base

  const int T0 = blockIdx.x * TPB;
  const float* ap = tok + (size_t)(T0 + n) * 1024 + kb + kg * 8;
  const float* wrow = (n < 3) ? (Wq + n * 1024)
                    : (n < 6) ? (Wk + (n - 3) * 1024)
                    : (n < 9) ? (Wv + (n - 6) * 1024) : Wq;
  const bool wvalid = (n < 9);
  const float* bp = wrow + kb + kg * 8;

  f32x4 acc = {0.f, 0.f, 0.f, 0.f};

  // ---- 1-step-lookahead pipeline over 4 steps of k=32 ----
  f4 A[2][2], B[2][2];
  A[0][0] = *(const f4*)(ap);
  A[0][1] = *(const f4*)(ap + 4);
  B[0][0] = *(const f4*)(bp);
  B[0][1] = *(const f4*)(bp + 4);

#pragma unroll
  for (int s = 0; s < 4; ++s) {
    const int cs = s & 1, ns = cs ^ 1;            // compile-time after unroll
    if (s < 3) {
      A[ns][0] = *(const f4*)(ap + (s + 1) * 32);
      A[ns][1] = *(const f4*)(ap + (s + 1) * 32 + 4);
      B[ns][0] = *(const f4*)(bp + (s + 1) * 32);
      B[ns][1] = *(const f4*)(bp + (s + 1) * 32 + 4);
    }
    s16x8 a = pack8(A[cs][0], A[cs][1]);
    f4 b0 = wvalid ? B[cs][0] : (f4)0.0f;
    f4 b1 = wvalid ? B[cs][1] : (f4)0.0f;
    s16x8 b = pack8(b0, b1);
    acc = __builtin_amdgcn_mfma_f32_16x16x32_bf16(a, b, acc, 0, 0, 0);
  }

  // ---- write this wave's k-partial C tile ----
#pragma unroll
  for (int i = 0; i < 4; ++i) {
    const int row = kg * 4 + i;                   // token-in-tile (R6-verified layout)
    clds[wv * 256 + row * 16 + n] = acc[i];
  }
  __syncthreads();

  // ---- 16 parallel softmaxes (threads 0..15, one token each) ----
  if (tid < TPB) {
    float r[9];
#pragma unroll
    for (int j = 0; j < 9; ++j) {
      float v = 0.0f;
#pragma unroll
      for (int w8 = 0; w8 < 8; ++w8) v += clds[w8 * 256 + tid * 16 + j];
      r[j] = v;
    }
    // q=r[0..2], k=r[3..5], v=r[6..8]
    float lg[3];
#pragma unroll
    for (int e = 0; e < 3; ++e) {
      float e0 = __expf(r[e] * r[3]);
      float e1 = __expf(r[e] * r[4]);
      float e2 = __expf(r[e] * r[5]);
      float den = (e0 + e1) + e2;
      float num = e0 * r[6] + e1 * r[7] + e2 * r[8];
      lg[e] = num * __builtin_amdgcn_rcpf(den);
    }
    float u0 = __expf(lg[0]);
    float u1 = __expf(lg[1]);
    float u2 = __expf(lg[2]);
    float rs = __builtin_amdgcn_rcpf((u0 + u1) + u2);
    float* op = out + (size_t)(T0 + tid) * 3;
    op[0] = u0 * rs;
    op[1] = u1 * rs;
    op[2] = u2 * rs;
  }
}

extern "C" void kernel_launch(void* const* d_in, const int* in_sizes, int n_in,
                              void* d_out, int out_size, void* d_ws, size_t ws_size,
                              hipStream_t stream) {
  const float* tok = (const float*)d_in[0];
  const float* Wq  = (const float*)d_in[1];
  const float* Wk  = (const float*)d_in[2];
  const float* Wv  = (const float*)d_in[3];
  float* out = (float*)d_out;

  const int n_tokens = in_sizes[0] / 1024;   // 32768
  const int blocks   = n_tokens / TPB;       // 2048

  hipLaunchKernelGGL(moa_k8, dim3(blocks), dim3(512), 0, stream,
                     tok, Wq, Wk, Wv, out);
}

// Round 14
// 26.459 us; speedup vs baseline: 1.2750x; 1.2750x over previous
//
#include <hip/hip_runtime.h>
#include <hip/hip_bf16.h>

typedef float f4 __attribute__((ext_vector_type(4)));
typedef float f32x4 __attribute__((ext_vector_type(4)));
typedef short s16x8 __attribute__((ext_vector_type(8)));

// R11 MFMA-direct datapath, amortization x2: block = 4 waves = 64 tokens,
// wave w owns k-quarter [w*256,+256) of FOUR 16-token tiles. B-frag
// prologue (16 loads+packs) now covers 32 MFMAs instead of 16; per-block
// fixed costs halve (512 blocks). Per step: 8 independent A-loads ->
// 4 pack8 -> 4 MFMAs sharing one bfrag. No wvalid selects: expert cols
// 9..15 read a clamped valid W row; their products land in C columns
// that the epilogue never reads. Epilogue: 16 KB LDS combine of the 4
// k-quarter partials + 64 parallel softmaxes.

#define TPB 64   // tokens per block

__device__ __forceinline__ s16x8 pack8(f4 a, f4 b) {
  union { s16x8 v; __hip_bfloat162 h[4]; } u;
  u.h[0] = __float22bfloat162_rn({a.x, a.y});
  u.h[1] = __float22bfloat162_rn({a.z, a.w});
  u.h[2] = __float22bfloat162_rn({b.x, b.y});
  u.h[3] = __float22bfloat162_rn({b.z, b.w});
  return u.v;
}

__global__ __launch_bounds__(256)
void moa_mfma4(const float* __restrict__ tok,
               const float* __restrict__ Wq,
               const float* __restrict__ Wk,
               const float* __restrict__ Wv,
               float* __restrict__ out) {
  __shared__ float clds[4 * 64 * 16];             // 16 KB: [wave][64 tok][16 col]
  const int tid  = threadIdx.x;
  const int wv   = tid >> 6;
  const int lane = tid & 63;
  const int n    = lane & 15;                     // A: token row / B: expert col
  const int kg   = lane >> 4;                     // k-group of 8
  const int kq   = wv * 256;                      // wave's k-quarter

  // ---- B-frags: this wave's weight quarter, bf16, 8 steps ----
  const float* wrow = (n < 3) ? (Wq + n * 1024)
                    : (n < 6) ? (Wk + (n - 3) * 1024)
                    : (Wv + ((n < 9) ? (n - 6) : 0) * 1024);   // clamp: cols 9..15 unused
  s16x8 bfrag[8];
#pragma unroll
  for (int s = 0; s < 8; ++s) {
    const float* p = wrow + kq + s * 32 + kg * 8;
    bfrag[s] = pack8(*(const f4*)p, *(const f4*)(p + 4));
  }

  // ---- A: four 16-token tiles per wave ----
  const int T0 = blockIdx.x * TPB;
  const float* ap = tok + (size_t)(T0 + n) * 1024 + kq + kg * 8;  // tile t: +t*16*1024

  f32x4 acc[4];
#pragma unroll
  for (int t = 0; t < 4; ++t) acc[t] = (f32x4){0.f, 0.f, 0.f, 0.f};

  // ---- 2-slot ring (1-ahead), 8 loads in flight per wave ----
  f4 A[2][4][2];
#pragma unroll
  for (int t = 0; t < 4; ++t) {
    A[0][t][0] = *(const f4*)(ap + t * 16384);
    A[0][t][1] = *(const f4*)(ap + t * 16384 + 4);
  }

#pragma unroll
  for (int s = 0; s < 8; ++s) {
    const int cs = s & 1, ns = cs ^ 1;            // compile-time after unroll
    if (s < 7) {
#pragma unroll
      for (int t = 0; t < 4; ++t) {
        A[ns][t][0] = *(const f4*)(ap + t * 16384 + (s + 1) * 32);
        A[ns][t][1] = *(const f4*)(ap + t * 16384 + (s + 1) * 32 + 4);
      }
    }
#pragma unroll
    for (int t = 0; t < 4; ++t) {
      s16x8 a = pack8(A[cs][t][0], A[cs][t][1]);
      acc[t] = __builtin_amdgcn_mfma_f32_16x16x32_bf16(a, bfrag[s], acc[t], 0, 0, 0);
    }
  }

  // ---- write this wave's k-partial C tiles ----
#pragma unroll
  for (int t = 0; t < 4; ++t)
#pragma unroll
    for (int i = 0; i < 4; ++i) {
      const int row = t * 16 + kg * 4 + i;        // token-in-block (R6-verified layout)
      clds[wv * 1024 + row * 16 + n] = acc[t][i];
    }
  __syncthreads();

  // ---- 64 parallel softmaxes (threads 0..63, one token each) ----
  if (tid < TPB) {
    float r[9];
#pragma unroll
    for (int j = 0; j < 9; ++j)
      r[j] = (clds[tid * 16 + j] + clds[1024 + tid * 16 + j]) +
             (clds[2048 + tid * 16 + j] + clds[3072 + tid * 16 + j]);
    // q=r[0..2], k=r[3..5], v=r[6..8]
    float lg[3];
#pragma unroll
    for (int e = 0; e < 3; ++e) {
      float e0 = __expf(r[e] * r[3]);
      float e1 = __expf(r[e] * r[4]);
      float e2 = __expf(r[e] * r[5]);
      float den = (e0 + e1) + e2;
      float num = e0 * r[6] + e1 * r[7] + e2 * r[8];
      lg[e] = num * __builtin_amdgcn_rcpf(den);
    }
    float u0 = __expf(lg[0]);
    float u1 = __expf(lg[1]);
    float u2 = __expf(lg[2]);
    float rs = __builtin_amdgcn_rcpf((u0 + u1) + u2);
    float* op = out + (size_t)(T0 + tid) * 3;
    op[0] = u0 * rs;
    op[1] = u1 * rs;
    op[2] = u2 * rs;
  }
}

extern "C" void kernel_launch(void* const* d_in, const int* in_sizes, int n_in,
                              void* d_out, int out_size, void* d_ws, size_t ws_size,
                              hipStream_t stream) {
  const float* tok = (const float*)d_in[0];
  const float* Wq  = (const float*)d_in[1];
  const float* Wk  = (const float*)d_in[2];
  const float* Wv  = (const float*)d_in[3];
  float* out = (float*)d_out;

  const int n_tokens = in_sizes[0] / 1024;   // 32768
  const int blocks   = n_tokens / TPB;       // 512

  hipLaunchKernelGGL(moa_mfma4, dim3(blocks), dim3(256), 0, stream,
                     tok, Wq, Wk, Wv, out);
}